// Round 1
// baseline (500.513 us; speedup 1.0000x reference)
//
#include <hip/hip_runtime.h>

#define BB 32
#define NN 300
#define HH 1024
#define WW 1024
#define RSTRIP 8                 // rows per block strip
#define NSTRIP (HH / RSTRIP)     // 128 strips per batch
#define SSTRIDE (BB * NN)        // 9600 floats per strip-slice

// One block per (batch, 8-row strip); 512 threads = 8 waves, one row per
// wave (16 cols/lane). Row-wise inclusive prefix of g = seg[2] - seg[1]
// parked in 32 KiB LDS, then each of the 300 boxes of the batch is resolved
// by one thread against the strip.
//
// v2: NO GLOBAL ATOMICS. Previously 4096 blocks x 300 atomicAdds hit the
// same 150 cache lines (~8200 same-line RMWs each) from all 8 XCDs --
// device-scope same-line atomics serialize at the coherence point and
// dominated the kernel (~200 of 246 us). Now each block stores its 300
// partials (zero if no overlap) to boxacc[s][b*300+t] -- a 1.2 KB coalesced
// store, zero contention -- and finalize reduces over the 128 strips.
// __launch_bounds__(512,8): cap 64 VGPR -> 4 blocks/CU = 32 waves/CU (full).
__global__ __launch_bounds__(512, 8) void strip_kernel(
    const float* __restrict__ seg,
    const float4* __restrict__ boxes,
    const float* __restrict__ conf,
    float* __restrict__ boxacc)
{
    int blk  = blockIdx.x;
    int b    = blk >> 7;          // / NSTRIP
    int s    = blk & (NSTRIP - 1);
    int r0   = s * RSTRIP;
    int t    = threadIdx.x;
    int lane = t & 63;
    int warp = t >> 6;            // 0..7 -> row within strip

    __shared__ float L[RSTRIP][WW];

    const float* p1 = seg + ((size_t)b * 3 + 1) * ((size_t)HH * WW);
    const float* p2 = seg + ((size_t)b * 3 + 2) * ((size_t)HH * WW);
    const float* q1 = p1 + (size_t)(r0 + warp) * WW + lane * 16;
    const float* q2 = p2 + (size_t)(r0 + warp) * WW + lane * 16;

    // Box metadata load issued early to overlap with the streaming loads.
    bool hasbox = t < NN;
    float4 bx = make_float4(0.f, 0.f, 0.f, 0.f);
    float cf = 0.f;
    if (hasbox) { bx = boxes[b * NN + t]; cf = conf[b * NN + t]; }

    float4 u0 = *(const float4*)(q2 +  0), v0 = *(const float4*)(q1 +  0);
    float4 u1 = *(const float4*)(q2 +  4), v1 = *(const float4*)(q1 +  4);
    float4 u2 = *(const float4*)(q2 +  8), v2 = *(const float4*)(q1 +  8);
    float4 u3 = *(const float4*)(q2 + 12), v3 = *(const float4*)(q1 + 12);

    float g[16];
    g[ 0]=u0.x-v0.x; g[ 1]=u0.y-v0.y; g[ 2]=u0.z-v0.z; g[ 3]=u0.w-v0.w;
    g[ 4]=u1.x-v1.x; g[ 5]=u1.y-v1.y; g[ 6]=u1.z-v1.z; g[ 7]=u1.w-v1.w;
    g[ 8]=u2.x-v2.x; g[ 9]=u2.y-v2.y; g[10]=u2.z-v2.z; g[11]=u2.w-v2.w;
    g[12]=u3.x-v3.x; g[13]=u3.y-v3.y; g[14]=u3.z-v3.z; g[15]=u3.w-v3.w;

    // sequential inclusive prefix over the lane's 16 elements
    float run = 0.f;
    #pragma unroll
    for (int j = 0; j < 16; ++j) { run += g[j]; g[j] = run; }
    // wave-wide exclusive scan of lane totals (wave = 64 lanes)
    float incl = run;
    #pragma unroll
    for (int d = 1; d < 64; d <<= 1) {
        float v = __shfl_up(incl, d, 64);
        if (lane >= d) incl += v;
    }
    float base = incl - run;
    float* Lr = &L[warp][lane * 16];
    *(float4*)(Lr +  0) = make_float4(g[ 0]+base, g[ 1]+base, g[ 2]+base, g[ 3]+base);
    *(float4*)(Lr +  4) = make_float4(g[ 4]+base, g[ 5]+base, g[ 6]+base, g[ 7]+base);
    *(float4*)(Lr +  8) = make_float4(g[ 8]+base, g[ 9]+base, g[10]+base, g[11]+base);
    *(float4*)(Lr + 12) = make_float4(g[12]+base, g[13]+base, g[14]+base, g[15]+base);
    __syncthreads();

    // Box phase: one box per thread (300 < 512). Unconditional store of the
    // partial (0 if invalid / no overlap) -- no atomics, no boxacc memset.
    if (hasbox) {
        float sum = 0.f;
        float x1f = (bx.x - 0.5f * bx.z) * (float)WW;
        float x2f = (bx.x + 0.5f * bx.z) * (float)WW;
        float y1f = (bx.y - 0.5f * bx.w) * (float)HH;
        float y2f = (bx.y + 0.5f * bx.w) * (float)HH;
        int x1 = min(max((int)truncf(x1f), 0), WW - 1);
        int x2 = min(max((int)truncf(x2f), 0), WW - 1);
        int y1 = min(max((int)truncf(y1f), 0), HH - 1);
        int y2 = min(max((int)truncf(y2f), 0), HH - 1);
        if ((cf >= 0.3f) && (x2 > x1) && (y2 > y1)) {
            int lo = max(y1, r0);
            int hi = min(y2 - 1, r0 + RSTRIP - 1);
            if (lo <= hi) {
                int xa = x2 - 1;
                int xb = x1 - 1;   // may be -1 -> contributes 0
                for (int r = lo; r <= hi; ++r) {
                    float v = L[r - r0][xa];
                    if (xb >= 0) v -= L[r - r0][xb];
                    sum += v;
                }
            }
        }
        boxacc[(size_t)s * SSTRIDE + b * NN + t] = sum;
    }
}

// Finalize: reduce the 128 per-strip partials per box, then
// relu(sum/area)*conf, mean over B*N. One atomic per block into the
// (pre-zeroed) output.
__global__ __launch_bounds__(256) void finalize_kernel(
    const float4* __restrict__ boxes,
    const float* __restrict__ conf,
    const float* __restrict__ boxacc,
    float* __restrict__ out)
{
    int i = blockIdx.x * 256 + threadIdx.x;
    float local = 0.f;
    if (i < BB * NN) {
        float acc = 0.f;
        #pragma unroll 16
        for (int s = 0; s < NSTRIP; ++s)
            acc += boxacc[(size_t)s * SSTRIDE + i];   // wave-coalesced, stride 9600
        float4 bx = boxes[i];
        float cf  = conf[i];
        float x1f = (bx.x - 0.5f * bx.z) * (float)WW;
        float x2f = (bx.x + 0.5f * bx.z) * (float)WW;
        float y1f = (bx.y - 0.5f * bx.w) * (float)HH;
        float y2f = (bx.y + 0.5f * bx.w) * (float)HH;
        int x1 = min(max((int)truncf(x1f), 0), WW - 1);
        int x2 = min(max((int)truncf(x2f), 0), WW - 1);
        int y1 = min(max((int)truncf(y1f), 0), HH - 1);
        int y2 = min(max((int)truncf(y2f), 0), HH - 1);
        if ((cf >= 0.3f) && (x2 > x1) && (y2 > y1)) {
            float area = (float)((y2 - y1) * (x2 - x1));
            local = fmaxf(acc / area, 0.f) * cf;
        }
    }
    #pragma unroll
    for (int d = 32; d > 0; d >>= 1)
        local += __shfl_down(local, d, 64);
    __shared__ float bsum[4];
    int lane = threadIdx.x & 63, warp = threadIdx.x >> 6;
    if (lane == 0) bsum[warp] = local;
    __syncthreads();
    if (threadIdx.x == 0) {
        float tsum = bsum[0] + bsum[1] + bsum[2] + bsum[3];
        atomicAdd(out, tsum * (1.0f / (BB * NN)));
    }
}

extern "C" void kernel_launch(void* const* d_in, const int* in_sizes, int n_in,
                              void* d_out, int out_size, void* d_ws, size_t ws_size,
                              hipStream_t stream) {
    const float4* boxes = (const float4*)d_in[0];  // (32,300,4)
    const float*  conf  = (const float*)d_in[1];   // (32,300)
    const float*  seg   = (const float*)d_in[2];   // (32,3,1024,1024)
    float* out    = (float*)d_out;
    float* boxacc = (float*)d_ws;                  // 128 * 9600 floats = 4.9 MB

    hipMemsetAsync(out, 0, sizeof(float), stream);
    strip_kernel<<<BB * NSTRIP, 512, 0, stream>>>(seg, boxes, conf, boxacc);
    finalize_kernel<<<(BB * NN + 255) / 256, 256, 0, stream>>>(boxes, conf, boxacc, out);
}